// Round 8
// baseline (383.745 us; speedup 1.0000x reference)
//
#include <hip/hip_runtime.h>
#include <math.h>

#define BDIM 256
#define BDIM2 512
typedef __bf16 bf16;
typedef __bf16 bf16x4 __attribute__((ext_vector_type(4)));
typedef __bf16 bf16x8 __attribute__((ext_vector_type(8)));
typedef float f32x4 __attribute__((ext_vector_type(4)));
typedef float f32x2 __attribute__((ext_vector_type(2)));

template <bool V> struct BC { static constexpr bool value = V; };

constexpr int B_ = 4, H_ = 768, W_ = 768;
constexpr int HW_ = H_ * W_;                 // 589824
constexpr int TS = 16;                       // conv spatial tile 16x16
constexpr int NTB = W_ / TS;                 // 48
constexpr int NBLK = HW_ / (TS * TS);        // 2304 blocks per sample
// head tile: 16 rows x 32 cols
constexpr int TSR = 16, TSC = 32;
constexpr int NTBC = W_ / TSC;               // 24
constexpr int NBLKH = (H_ / TSR) * NTBC;     // 1152 per sample

// scratch carved from the TAIL of d_out (written before read each iteration;
// the final conv2_sauvola of the last chunk overwrites it after last use):
constexpr int PMAX_FLOATS = 4 * NBLK * 48;          // 442368
constexpr int OUT_ELEMS   = B_ * HW_;               // 2359296

// XCD-aware bijective swizzle (R7, verified: L6 FETCH 55->46MB, dur 98->72):
// hw blocks {k,k+8,...} all dispatch to XCD k; remap makes them process
// CONSECUTIVE tiles -> halo overlap + layer->layer reuse hit per-XCD L2.
// Requires n%8==0 (all grids are).
__device__ inline int xcd_swz(int b, int n) {
    const int q = n >> 3;
    return (b & 7) * q + (b >> 3);
}

// ---------------------------------------------------------------------------
// Weight repack: [COUT][CIN][3][3] fp32 -> padded bf16 [NT*16][KPP],
// k = tap*CINP + ci, zero everywhere outside (n<COUT, tap<9, ci<CIN).
// ---------------------------------------------------------------------------
__device__ void repack_one(const float* __restrict__ src, bf16* __restrict__ dst,
                           int CIN, int CINP, int COUT, int NT16, int KPP)
{
    const int n_ = NT16 * KPP;
    for (int idx = threadIdx.x; idx < n_; idx += BDIM) {
        const int n = idx / KPP, k = idx - n * KPP;
        const int tap = k / CINP, ci = k - tap * CINP;
        float v = 0.f;
        if (n < COUT && tap < 9 && ci < CIN)
            v = src[(n * CIN + ci) * 9 + tap];
        dst[idx] = (bf16)v;
    }
}

__global__ __launch_bounds__(BDIM) void repack_all(
    const float* w0, const float* w1, const float* w2, const float* w3,
    const float* w4, const float* w5, const float* wf,
    bf16* r0, bf16* r1, bf16* r2, bf16* r3, bf16* r4, bf16* r5, bf16* rf)
{
    switch (blockIdx.x) {
        case 0: repack_one(w0, r0, 1,  8,  4,  16, 104); break;
        case 1: repack_one(w1, r1, 4,  8,  8,  16, 104); break;
        case 2: repack_one(w2, r2, 8,  8,  12, 16, 104); break;
        case 3: repack_one(w3, r3, 12, 16, 16, 16, 168); break;
        case 4: repack_one(w4, r4, 16, 16, 20, 32, 168); break;
        case 5: repack_one(w5, r5, 20, 24, 24, 32, 232); break;
        case 6: repack_one(wf, rf, 24, 24, 6,  16, 232); break;
    }
}

// ---------------------------------------------------------------------------
// bf16-MFMA conv 3x3 (dilated, SAME) + bias, NHWC, TS=16 tiles, 256 thr.
// R8: staging is 2-deep software-pipelined — both iterations' global loads
// issue into registers BEFORE any convert/pack, hiding the 2nd load's
// latency under the 1st's processing (each kernel is latency-bound:
// VALU 46% + MFMA 19% = 65% issue at 44% occupancy).
// LESSONS pinned: (R4) TS=32 halves occupancy — NO; (R5/R11) NO high-rate
// device atomics/fences — 74ns per same-line RMW. Stats = per-block
// partials (transposed, coalesced) + tiny reduce kernel.
// Stats layout: prevStats[c] = (scale, beta) = (invstd, -mean*invstd).
// ---------------------------------------------------------------------------
template <int CIN, int CINP, int COUT, int DIL, bool FIRST>
__global__ __launch_bounds__(BDIM) void conv_mfma(
    const void* __restrict__ inv,        // FIRST: fp32 x; else bf16 y_prev
    const float* __restrict__ prevStats, // [nb][CIN][2] (scale, beta)
    const bf16* __restrict__ wp,         // packed [NT*16][KPP]
    const float* __restrict__ bias,      // [COUT] fp32
    bf16* __restrict__ y,                // [nb][H][W][COUT]
    float* __restrict__ partials,        // [2*COUT][nb*NBLK]
    int NBT)                             // nb*NBLK
{
    constexpr int TW = TS + 2 * DIL;
    constexpr int KP = ((9 * CINP + 31) / 32) * 32;
    constexpr int KPP = KP + 8;
    constexpr int NT = (COUT + 15) / 16;
    constexpr int KS = KP / 32;
    constexpr int CSTR = (CINP == 16) ? 24 : CINP;   // bank-spread (see R7 notes)
    constexpr int NLOC = TW * TW;                    // <= 400 = 2 iterations
    constexpr int N8 = CIN / 8;
    constexpr int N4 = (CIN % 8) / 4;                // 0 or 1
    __shared__ __align__(16) bf16 tile[NLOC * CSTR];
    __shared__ float sred[4][2 * COUT];

    const int bid = xcd_swz(blockIdx.x, gridDim.x);
    const int s = bid / NBLK;
    const int blk = bid - s * NBLK;
    const int ti = blk / NTB, tj = blk - ti * NTB;
    const int i0 = ti * TS - DIL, j0 = tj * TS - DIL;
    const int t = threadIdx.x;
    const bool interior = (i0 >= 0) & (j0 >= 0) &
                          (i0 + TW <= H_) & (j0 + TW <= W_);

    // ---- stage halo tile: 2-deep pipelined (R8) ----
    const float* ps = prevStats + s * 2 * CIN;
    auto stage = [&](auto bc) {
        constexpr bool IN = decltype(bc)::value;
        const int loc1 = t + BDIM;
        const bool act1 = loc1 < NLOC;
        int gi[2], gj[2];
        bool ok[2];
        {
            const int rr0 = t / TW, cc0 = t - rr0 * TW;
            gi[0] = i0 + rr0; gj[0] = j0 + cc0;
            const int rr1 = loc1 / TW, cc1 = loc1 - rr1 * TW;
            gi[1] = i0 + rr1; gj[1] = j0 + cc1;
        }
        if constexpr (IN) {
            ok[0] = true; ok[1] = act1;
        } else {
            ok[0] = (gi[0] >= 0) & (gi[0] < H_) & (gj[0] >= 0) & (gj[0] < W_);
            ok[1] = act1 & (gi[1] >= 0) & (gi[1] < H_) & (gj[1] >= 0) & (gj[1] < W_);
        }

        // phase 1: issue all global loads into registers
        float xf[2];
        bf16x8 r8[2][N8 ? N8 : 1];
        bf16x4 r4[2];
#pragma unroll
        for (int d = 0; d < 2; ++d) {
            if constexpr (FIRST) {
                xf[d] = 0.f;
                if (ok[d])
                    xf[d] = ((const float*)inv)[(size_t)s * HW_ +
                                                (size_t)gi[d] * W_ + gj[d]];
            } else {
                if (ok[d]) {
                    const bf16* ing = (const bf16*)inv +
                        ((size_t)s * HW_ + (size_t)gi[d] * W_ + gj[d]) * CIN;
#pragma unroll
                    for (int qq = 0; qq < N8; ++qq)
                        r8[d][qq] = ((const bf16x8*)ing)[qq];
                    if constexpr (N4)
                        r4[d] = ((const bf16x4*)ing)[2 * N8];
                }
            }
        }

        // phase 2: convert + pack + LDS write (both iterations)
#pragma unroll
        for (int d = 0; d < 2; ++d) {
            if (d == 1 && !act1) break;
            float lv[CSTR];
#pragma unroll
            for (int c = 0; c < CSTR; ++c) lv[c] = 0.f;
            if constexpr (FIRST) {
                lv[0] = xf[d];
            } else {
                if (ok[d]) {
#pragma unroll
                    for (int qq = 0; qq < N8; ++qq)
#pragma unroll
                        for (int u = 0; u < 8; ++u) {
                            const int ci = 8 * qq + u;
                            lv[ci] = fmaxf(fmaf((float)r8[d][qq][u], ps[2 * ci], ps[2 * ci + 1]), 0.f);
                        }
                    if constexpr (N4)
#pragma unroll
                        for (int u = 0; u < 4; ++u) {
                            const int ci = 8 * N8 + u;
                            lv[ci] = fmaxf(fmaf((float)r4[d][u], ps[2 * ci], ps[2 * ci + 1]), 0.f);
                        }
                }
            }
            bf16* lp = tile + (t + d * BDIM) * CSTR;
#pragma unroll
            for (int g = 0; g < CSTR / 8; ++g) {
                bf16x8 pk;
#pragma unroll
                for (int u = 0; u < 8; ++u) pk[u] = (bf16)lv[8 * g + u];
                *(bf16x8*)(lp + 8 * g) = pk;
            }
        }
    };
    if (interior) stage(BC<true>{}); else stage(BC<false>{});
    __syncthreads();

    // ---- MFMA K-loop, software-pipelined 1 ks ahead ----
    const int wave = t >> 6, lane = t & 63, q = lane >> 4, ln = lane & 15;
    f32x4 acc[4][NT];
#pragma unroll
    for (int mt = 0; mt < 4; ++mt)
#pragma unroll
        for (int u = 0; u < NT; ++u) acc[mt][u] = (f32x4){0.f, 0.f, 0.f, 0.f};

    auto aOff = [&](int ks) -> int {
        int k0 = ks * 32 + q * 8;
        int tap = k0 / CINP;
        int ci0 = k0 - tap * CINP;
        if (tap > 8) { tap = 0; ci0 = 0; }   // padded k: B rows are zero
        const int ky = tap / 3, kx = tap - 3 * ky;
        return (ky * DIL * TW + kx * DIL) * CSTR + ci0;
    };

    bf16x8 bfr[NT], bfrN[NT];
    bf16x8 af[4], afN[4];
#pragma unroll
    for (int u = 0; u < NT; ++u)
        bfr[u] = *(const bf16x8*)&wp[(u * 16 + ln) * KPP + q * 8];
    {
        const int ao = aOff(0);
#pragma unroll
        for (int mt = 0; mt < 4; ++mt)
            af[mt] = *(const bf16x8*)&tile[((wave * 4 + mt) * TW + ln) * CSTR + ao];
    }

#pragma unroll
    for (int ks = 0; ks < KS; ++ks) {
        if (ks + 1 < KS) {
#pragma unroll
            for (int u = 0; u < NT; ++u)
                bfrN[u] = *(const bf16x8*)&wp[(u * 16 + ln) * KPP + (ks + 1) * 32 + q * 8];
            const int ao = aOff(ks + 1);
#pragma unroll
            for (int mt = 0; mt < 4; ++mt)
                afN[mt] = *(const bf16x8*)&tile[((wave * 4 + mt) * TW + ln) * CSTR + ao];
        }
#pragma unroll
        for (int mt = 0; mt < 4; ++mt)
#pragma unroll
            for (int u = 0; u < NT; ++u)
                acc[mt][u] = __builtin_amdgcn_mfma_f32_16x16x32_bf16(
                    af[mt], bfr[u], acc[mt][u], 0, 0, 0);
#pragma unroll
        for (int u = 0; u < NT; ++u) bfr[u] = bfrN[u];
#pragma unroll
        for (int mt = 0; mt < 4; ++mt) af[mt] = afN[mt];
    }

    // ---- bias + stats (registers), sred ----
#pragma unroll
    for (int u = 0; u < NT; ++u) {
        const int n = u * 16 + ln;
        const float bv = (n < COUT) ? bias[n] : 0.f;
        float s1 = 0.f, s2 = 0.f;
#pragma unroll
        for (int mt = 0; mt < 4; ++mt)
#pragma unroll
            for (int r = 0; r < 4; ++r) {
                const float v = acc[mt][u][r] + bv;
                acc[mt][u][r] = v;
                s1 += v; s2 += v * v;
            }
        s1 += __shfl_xor(s1, 16); s1 += __shfl_xor(s1, 32);
        s2 += __shfl_xor(s2, 16); s2 += __shfl_xor(s2, 32);
        if (lane < 16 && n < COUT) { sred[wave][n] = s1; sred[wave][COUT + n] = s2; }
    }
    __syncthreads();   // K-loop tile reads complete + sred visible
    if (t < 2 * COUT) {
        partials[(size_t)t * NBT + (size_t)s * NBLK + blk] =
            sred[0][t] + sred[1][t] + sred[2][t] + sred[3][t];
    }

    // ---- out-stage into LDS (reuse tile), then coalesced global stores ----
    bf16* ost = tile;   // 256*COUT bf16 <= tile capacity for all layers
#pragma unroll
    for (int u = 0; u < NT; ++u) {
        const int n = u * 16 + ln;
        if (n < COUT) {
#pragma unroll
            for (int mt = 0; mt < 4; ++mt)
#pragma unroll
                for (int r = 0; r < 4; ++r) {
                    const int pl = (wave * 4 + mt) * 16 + q * 4 + r;
                    ost[pl * COUT + n] = (bf16)acc[mt][u][r];
                }
        }
    }
    __syncthreads();

    const int lr = t >> 4, lc = t & 15;
    bf16* yp = y + (size_t)s * HW_ * COUT +
               ((size_t)(ti * TS + lr) * W_ + (tj * TS + lc)) * COUT;
    const bf16* sp = ost + t * COUT;
    if constexpr (COUT % 8 == 0) {
#pragma unroll
        for (int g = 0; g < COUT / 8; ++g)
            ((bf16x8*)yp)[g] = ((const bf16x8*)sp)[g];
    } else {
#pragma unroll
        for (int g = 0; g < COUT / 4; ++g)
            ((bf16x4*)yp)[g] = ((const bf16x4*)sp)[g];
    }
}

// ---------------------------------------------------------------------------
// Reduce transposed partials -> (scale, beta) per (sample, channel):
// scale = invstd, beta = -mean*invstd  (consumer norm = fma(raw,scale,beta))
// ---------------------------------------------------------------------------
template <int COUT>
__global__ __launch_bounds__(BDIM) void reduce_stats(
    const float* __restrict__ partials, float* __restrict__ stats, int NBT)
{
    const int s = blockIdx.x / COUT;
    const int co = blockIdx.x - s * COUT;
    const float* P1 = partials + (size_t)co * NBT + (size_t)s * NBLK;
    const float* P2 = partials + (size_t)(COUT + co) * NBT + (size_t)s * NBLK;
    float s1 = 0.f, s2 = 0.f;
    for (int k = threadIdx.x; k < NBLK; k += BDIM) {
        s1 += P1[k];
        s2 += P2[k];
    }
#pragma unroll
    for (int off = 32; off; off >>= 1) {
        s1 += __shfl_xor(s1, off);
        s2 += __shfl_xor(s2, off);
    }
    __shared__ float l1[4], l2[4];
    const int lane = threadIdx.x & 63, wave = threadIdx.x >> 6;
    if (lane == 0) { l1[wave] = s1; l2[wave] = s2; }
    __syncthreads();
    if (threadIdx.x == 0) {
        float t1 = l1[0] + l1[1] + l1[2] + l1[3];
        float t2 = l2[0] + l2[1] + l2[2] + l2[3];
        float m = t1 / (float)HW_;
        float var = t2 / (float)HW_ - m * m;
        const float rs = rsqrtf(var + 1e-5f);
        stats[((size_t)s * COUT + co) * 2 + 0] = rs;
        stats[((size_t)s * COUT + co) * 2 + 1] = -m * rs;
    }
}

// ---------------------------------------------------------------------------
// Merged head (16x32 tile, 512 threads, 1 px/thread): conv2 (24->6, dil 1,
// MFMA, folded norm of L5) + channel softmax (registers) + fused Sauvola via
// LOCAL 34x50 float2 integral image in LDS. Segmented scans + fast-math
// intrinsics (R7). R8: 2-deep pipelined staging for the conv tile and the
// I12 halo (2x 2-deep groups).
// ---------------------------------------------------------------------------
__global__ __launch_bounds__(BDIM2) void conv2_sauvola(
    const bf16* __restrict__ in, const float* __restrict__ prevStats,
    const bf16* __restrict__ wp, const float* __restrict__ bias,
    const float* __restrict__ x,
    const float* __restrict__ kArr, const float* __restrict__ RArr,
    const float* __restrict__ alphaP, float* __restrict__ outp)
{
    constexpr int CIN = 24, CINP = 24, COUT = 6;
    constexpr int TWR = TSR + 2;          // 18 halo rows
    constexpr int TWC = TSC + 2;          // 34 halo cols
    constexpr int KPP = 232, KS = 7, CSTR = 24;
    constexpr int R9 = 9;                 // max window radius (19>>1)
    constexpr int HR = TSR + 2 * R9;      // 34 I12 data rows
    constexpr int HC = TSC + 2 * R9;      // 50 I12 data cols
    constexpr int IST = 51;               // integral-image stride in float2
    constexpr int SLOG_STR = 7;           // gcd(7,32)=1 -> conflict-light
    constexpr int NLOC = TWR * TWC;       // 612 -> 2 iterations @512
    constexpr int N8 = CIN / 8;           // 3
    __shared__ __align__(16) bf16 tile[NLOC * CSTR];          // 29376 B
    __shared__ __align__(16) f32x2 I12[(HR + 1) * IST];       // 14280 B

    const int bid = xcd_swz(blockIdx.x, gridDim.x);
    const int s = bid / NBLKH;
    const int blk = bid - s * NBLKH;
    const int ti = blk / NTBC, tj = blk - ti * NTBC;   // ti 0..47, tj 0..23
    const int i0 = ti * TSR - 1, j0 = tj * TSC - 1;
    const int is0 = ti * TSR - R9, js0 = tj * TSC - R9;
    const int t = threadIdx.x;
    const float* xs = x + (size_t)s * HW_;
    const bool interior = (is0 >= 0) & (js0 >= 0) &
                          (is0 + HR <= H_) & (js0 + HC <= W_);

    // ---- stage conv2 tile (2-deep) + 34x50 x-halo into I12 (2x 2-deep) ----
    const float* ps = prevStats + s * 2 * CIN;
    auto stage = [&](auto bc) {
        constexpr bool IN = decltype(bc)::value;
        // conv tile: iterations {t, t+512}
        {
            const int loc1 = t + BDIM2;
            const bool act1 = loc1 < NLOC;
            int gi[2], gj[2];
            bool ok[2];
            {
                const int rr0 = t / TWC, cc0 = t - rr0 * TWC;
                gi[0] = i0 + rr0; gj[0] = j0 + cc0;
                const int rr1 = loc1 / TWC, cc1 = loc1 - rr1 * TWC;
                gi[1] = i0 + rr1; gj[1] = j0 + cc1;
            }
            if constexpr (IN) {
                ok[0] = true; ok[1] = act1;
            } else {
                ok[0] = (gi[0] >= 0) & (gi[0] < H_) & (gj[0] >= 0) & (gj[0] < W_);
                ok[1] = act1 & (gi[1] >= 0) & (gi[1] < H_) & (gj[1] >= 0) & (gj[1] < W_);
            }
            bf16x8 r8[2][N8];
#pragma unroll
            for (int d = 0; d < 2; ++d) {
                if (ok[d]) {
                    const bf16* ing = in +
                        ((size_t)s * HW_ + (size_t)gi[d] * W_ + gj[d]) * CIN;
#pragma unroll
                    for (int qq = 0; qq < N8; ++qq)
                        r8[d][qq] = ((const bf16x8*)ing)[qq];
                }
            }
#pragma unroll
            for (int d = 0; d < 2; ++d) {
                if (d == 1 && !act1) break;
                float lv[CSTR];
#pragma unroll
                for (int c = 0; c < CSTR; ++c) lv[c] = 0.f;
                if (ok[d]) {
#pragma unroll
                    for (int qq = 0; qq < N8; ++qq)
#pragma unroll
                        for (int u = 0; u < 8; ++u) {
                            const int ci = 8 * qq + u;
                            lv[ci] = fmaxf(fmaf((float)r8[d][qq][u], ps[2 * ci], ps[2 * ci + 1]), 0.f);
                        }
                }
                bf16* lp = tile + (t + d * BDIM2) * CSTR;
#pragma unroll
                for (int g = 0; g < CSTR / 8; ++g) {
                    bf16x8 pk;
#pragma unroll
                    for (int u = 0; u < 8; ++u) pk[u] = (bf16)lv[8 * g + u];
                    *(bf16x8*)(lp + 8 * g) = pk;
                }
            }
        }
        // I12 halo: 1700 locs -> two 2-deep groups
#pragma unroll
        for (int base = 0; base < HR * HC; base += 2 * BDIM2) {
            const int l0 = base + t, l1 = base + BDIM2 + t;
            const bool a0 = l0 < HR * HC, a1 = l1 < HR * HC;
            float v0 = 0.f, v1 = 0.f;
            int rr0 = 0, cc0 = 0, rr1 = 0, cc1 = 0;
            if (a0) {
                rr0 = l0 / HC; cc0 = l0 - rr0 * HC;
                const int gi = is0 + rr0, gj = js0 + cc0;
                if constexpr (IN) v0 = xs[(size_t)gi * W_ + gj];
                else if ((gi >= 0) & (gi < H_) & (gj >= 0) & (gj < W_))
                    v0 = xs[(size_t)gi * W_ + gj];
            }
            if (a1) {
                rr1 = l1 / HC; cc1 = l1 - rr1 * HC;
                const int gi = is0 + rr1, gj = js0 + cc1;
                if constexpr (IN) v1 = xs[(size_t)gi * W_ + gj];
                else if ((gi >= 0) & (gi < H_) & (gj >= 0) & (gj < W_))
                    v1 = xs[(size_t)gi * W_ + gj];
            }
            if (a0) I12[(rr0 + 1) * IST + cc0 + 1] = (f32x2){v0, v0 * v0};
            if (a1) I12[(rr1 + 1) * IST + cc1 + 1] = (f32x2){v1, v1 * v1};
        }
    };
    if (interior) stage(BC<true>{}); else stage(BC<false>{});
    for (int idx = t; idx < IST + HR; idx += BDIM2) {
        if (idx < IST) I12[idx] = (f32x2){0.f, 0.f};              // row 0
        else I12[(idx - IST + 1) * IST] = (f32x2){0.f, 0.f};      // col 0
    }
    __syncthreads();

    // ---- conv2 MFMA K-loop: 8 waves x 4 M-tiles (M=512 px) ----
    const int wave = t >> 6, lane = t & 63, q = lane >> 4, ln = lane & 15;
    f32x4 acc[4];
#pragma unroll
    for (int mt = 0; mt < 4; ++mt) acc[mt] = (f32x4){0.f, 0.f, 0.f, 0.f};

    auto aOff = [&](int ks) -> int {
        int k0 = ks * 32 + q * 8;
        int tap = k0 / CINP;
        int ci0 = k0 - tap * CINP;
        if (tap > 8) { tap = 0; ci0 = 0; }
        const int ky = tap / 3, kx = tap - 3 * ky;
        return (ky * TWC + kx) * CSTR + ci0;
    };

#pragma unroll
    for (int ks = 0; ks < KS; ++ks) {
        const bf16x8 bfr = *(const bf16x8*)&wp[ln * KPP + ks * 32 + q * 8];
        const int ao = aOff(ks);
#pragma unroll
        for (int mt = 0; mt < 4; ++mt) {
            const int Mt = wave * 4 + mt;                 // 0..31
            const bf16x8 af = *(const bf16x8*)
                &tile[(((Mt >> 1)) * TWC + (Mt & 1) * 16 + ln) * CSTR + ao];
            acc[mt] = __builtin_amdgcn_mfma_f32_16x16x32_bf16(af, bfr, acc[mt], 0, 0, 0);
        }
    }
    __syncthreads();   // done reading tile -> reuse as logits

    // ---- phase A: logits -> slog ; row-SEGMENT scan (68 thr, 25 iters) ----
    float* slog = (float*)tile;            // 512*7*4 = 14336 B <= 29376 B
    const float bv = (ln < COUT) ? bias[ln] : 0.f;
#pragma unroll
    for (int mt = 0; mt < 4; ++mt)
#pragma unroll
        for (int r = 0; r < 4; ++r)
            if (ln < COUT) {
                const int pl = (wave * 4 + mt) * 16 + q * 4 + r;   // 0..511
                slog[pl * SLOG_STR + ln] = acc[mt][r] + bv;
            }
    if (t < 68) {
        const int row = (t < 34 ? t : t - 34) + 1;
        const int c0 = (t < 34) ? 1 : 26;
        f32x2* p = I12 + row * IST + c0;
        f32x2 a = p[0];
#pragma unroll 5
        for (int c = 1; c < 25; ++c) { a += p[c]; p[c] = a; }
    }
    __syncthreads();

    // ---- row fixup: cols 26..50 += row-left total (850 cells, all thr) ----
    for (int idx = t; idx < 34 * 25; idx += BDIM2) {
        const int row = idx / 25 + 1, col = idx % 25 + 26;
        I12[row * IST + col] += I12[row * IST + 25];
    }
    __syncthreads();

    // ---- col-SEGMENT scan (100 thr, 17 iters) + softmax (all thr) ----
    if (t < 100) {
        const int col = (t < 50 ? t : t - 50) + 1;
        const int r0 = (t < 50) ? 1 : 18;
        f32x2* p = I12 + r0 * IST + col;
        f32x2 a = *p;
#pragma unroll 4
        for (int r = 1; r < 17; ++r) { a += p[r * IST]; p[r * IST] = a; }
    }
    float e0[COUT];
    {
        float mx = slog[t * SLOG_STR];
#pragma unroll
        for (int co = 1; co < COUT; ++co) mx = fmaxf(mx, slog[t * SLOG_STR + co]);
        float sm = 0.f;
#pragma unroll
        for (int co = 0; co < COUT; ++co) { e0[co] = __expf(slog[t * SLOG_STR + co] - mx); sm += e0[co]; }
        const float inv = __builtin_amdgcn_rcpf(sm);
#pragma unroll
        for (int co = 0; co < COUT; ++co) e0[co] *= inv;
    }
    // per-window fused constants: th = Ex*(1 + k*(dev/R - 1)) = Ex*fma(dev,c0,c1)
    float c0w[6], c1w[6];
#pragma unroll
    for (int wi = 0; wi < 6; ++wi) {
        const float kk = kArr[wi], rr = RArr[wi];
        c0w[wi] = kk / rr;
        c1w[wi] = 1.f - kk;
    }
    // hoist per-pixel globals (load latency hides under the scans)
    const int pr0 = t >> 5, pc0 = t & 31;          // px: rows 0..15, cols 0..31
    const int gi0 = ti * TSR + pr0, gj0 = tj * TSC + pc0;
    const float xv0 = xs[(size_t)gi0 * W_ + gj0];
    const float alpha = alphaP[0];
    __syncthreads();

    // ---- col fixup: rows 18..34 += row-17 total (850 cells, all thr) ----
    for (int idx = t; idx < 17 * 50; idx += BDIM2) {
        const int row = idx / 50 + 18, col = idx % 50 + 1;
        I12[row * IST + col] += I12[17 * IST + col];
    }
    __syncthreads();   // integral image complete

    // ---- phase C: Sauvola (f = e0[] in registers) ----
    const int wins[6] = {3, 5, 7, 11, 15, 19};
    const float invc_tab[6] = {1.f / 9.f,  1.f / 25.f,  1.f / 49.f,
                               1.f / 121.f, 1.f / 225.f, 1.f / 361.f};
    float th1 = 0.f;
    if (interior) {
#pragma unroll
        for (int wi = 0; wi < 6; ++wi) {
            const int r = wins[wi] >> 1;
            const float invc = invc_tab[wi];
            const int top = pr0 + R9 - r, bot = pr0 + R9 + r + 1;
            const int lef = pc0 + R9 - r, rig = pc0 + R9 + r + 1;
            const f32x2 Atl = I12[top * IST + lef];
            const f32x2 Atr = I12[top * IST + rig];
            const f32x2 Abl = I12[bot * IST + lef];
            const f32x2 Abr = I12[bot * IST + rig];
            const f32x2 sm2 = Abr - Atr - Abl + Atl;
            const float Ex = sm2.x * invc;
            const float Ex2 = sm2.y * invc;
            const float dev = __builtin_amdgcn_sqrtf(fmaxf(Ex2 - Ex * Ex, 1e-6f));
            const float th = Ex * fmaf(dev, c0w[wi], c1w[wi]);
            th1 = fmaf(e0[wi], th, th1);
        }
    } else {
#pragma unroll
        for (int wi = 0; wi < 6; ++wi) {
            const int r = wins[wi] >> 1;
            const int r0 = max(gi0 - r, 0), r1i = min(gi0 + r, H_ - 1);
            const int c0 = max(gj0 - r, 0), c1 = min(gj0 + r, W_ - 1);
            const float invc = __builtin_amdgcn_rcpf((float)((r1i - r0 + 1) * (c1 - c0 + 1)));
            const int top = pr0 + R9 - r, bot = pr0 + R9 + r + 1;
            const int lef = pc0 + R9 - r, rig = pc0 + R9 + r + 1;
            const f32x2 Atl = I12[top * IST + lef];
            const f32x2 Atr = I12[top * IST + rig];
            const f32x2 Abl = I12[bot * IST + lef];
            const f32x2 Abr = I12[bot * IST + rig];
            const f32x2 sm2 = Abr - Atr - Abl + Atl;
            const float Ex = sm2.x * invc;
            const float Ex2 = sm2.y * invc;
            const float dev = __builtin_amdgcn_sqrtf(fmaxf(Ex2 - Ex * Ex, 1e-6f));
            const float th = Ex * fmaf(dev, c0w[wi], c1w[wi]);
            th1 = fmaf(e0[wi], th, th1);
        }
    }
    outp[(size_t)s * HW_ + (size_t)gi0 * W_ + gj0] = (xv0 - th1) * alpha;
}

// ---------------------------------------------------------------------------
extern "C" void kernel_launch(void* const* d_in, const int* in_sizes, int n_in,
                              void* d_out, int out_size, void* d_ws, size_t ws_size,
                              hipStream_t stream) {
    const float* x   = (const float*)d_in[0];
    const float* w0  = (const float*)d_in[1];  const float* b0 = (const float*)d_in[2];
    const float* w1  = (const float*)d_in[3];  const float* b1 = (const float*)d_in[4];
    const float* w2  = (const float*)d_in[5];  const float* b2 = (const float*)d_in[6];
    const float* w3  = (const float*)d_in[7];  const float* b3 = (const float*)d_in[8];
    const float* w4  = (const float*)d_in[9];  const float* b4 = (const float*)d_in[10];
    const float* w5  = (const float*)d_in[11]; const float* b5 = (const float*)d_in[12];
    const float* wf  = (const float*)d_in[13]; const float* bf = (const float*)d_in[14];
    const float* kA  = (const float*)d_in[15];
    const float* RA  = (const float*)d_in[16];
    const float* alp = (const float*)d_in[17];
    float* out = (float*)d_out;
    (void)n_in; (void)in_sizes; (void)out_size;

    // partials + stats live in the TAIL of d_out: each iteration writes them
    // before reading; only the final chunk's conv2_sauvola overwrites the
    // tail, and that happens after the last partials/stats use.
    float* partials = out + (OUT_ELEMS - PMAX_FLOATS - 256);
    float* stats    = out + (OUT_ELEMS - 224);

    // ---- choose samples-per-launch from ws_size (deterministic) ----
    auto need = [](int nb) -> size_t {
        size_t o = 0;
        auto al = [&](size_t bytes) { o += (bytes + 255) & ~(size_t)255; };
        al((size_t)nb * HW_ * 20 * 2);          // bufA (bf16)
        al((size_t)nb * HW_ * 24 * 2);          // bufB (bf16)
        al(1664 * 2); al(1664 * 2); al(1664 * 2); al(2688 * 2);
        al(5376 * 2); al(7424 * 2); al(3712 * 2);
        return o;
    };
    int nb = 1;
    if (ws_size >= need(4)) nb = 4;
    else if (ws_size >= need(2)) nb = 2;

    char* ws = (char*)d_ws;
    size_t off = 0;
    auto alloc = [&](size_t bytes) -> void* {
        void* p = ws + off;
        off += (bytes + 255) & ~(size_t)255;
        return p;
    };
    bf16*  bufA = (bf16*)alloc((size_t)nb * HW_ * 20 * 2);
    bf16*  bufB = (bf16*)alloc((size_t)nb * HW_ * 24 * 2);
    bf16* r0 = (bf16*)alloc(1664 * 2);
    bf16* r1 = (bf16*)alloc(1664 * 2);
    bf16* r2 = (bf16*)alloc(1664 * 2);
    bf16* r3 = (bf16*)alloc(2688 * 2);
    bf16* r4 = (bf16*)alloc(5376 * 2);
    bf16* r5 = (bf16*)alloc(7424 * 2);
    bf16* rf = (bf16*)alloc(3712 * 2);

    const dim3 blk(BDIM);
    const int cgc = nb * NBLK;      // conv grid (TS=16)
    const int cgh = nb * NBLKH;     // head grid (16x32)
    const int NBT = nb * NBLK;

    repack_all<<<7, blk, 0, stream>>>(w0, w1, w2, w3, w4, w5, wf,
                                      r0, r1, r2, r3, r4, r5, rf);

    for (int it = 0; it < B_ / nb; ++it) {
        const float* xc   = x   + (size_t)it * nb * HW_;
        float*       outc = out + (size_t)it * nb * HW_;

        conv_mfma<1, 8, 4, 1, true><<<cgc, blk, 0, stream>>>(xc, nullptr, r0, b0, bufA, partials, NBT);
        reduce_stats<4><<<nb * 4, blk, 0, stream>>>(partials, stats, NBT);

        conv_mfma<4, 8, 8, 2, false><<<cgc, blk, 0, stream>>>(bufA, stats, r1, b1, bufB, partials, NBT);
        reduce_stats<8><<<nb * 8, blk, 0, stream>>>(partials, stats, NBT);

        conv_mfma<8, 8, 12, 2, false><<<cgc, blk, 0, stream>>>(bufB, stats, r2, b2, bufA, partials, NBT);
        reduce_stats<12><<<nb * 12, blk, 0, stream>>>(partials, stats, NBT);

        conv_mfma<12, 16, 16, 2, false><<<cgc, blk, 0, stream>>>(bufA, stats, r3, b3, bufB, partials, NBT);
        reduce_stats<16><<<nb * 16, blk, 0, stream>>>(partials, stats, NBT);

        conv_mfma<16, 16, 20, 2, false><<<cgc, blk, 0, stream>>>(bufB, stats, r4, b4, bufA, partials, NBT);
        reduce_stats<20><<<nb * 20, blk, 0, stream>>>(partials, stats, NBT);

        conv_mfma<20, 24, 24, 2, false><<<cgc, blk, 0, stream>>>(bufA, stats, r5, b5, bufB, partials, NBT);
        reduce_stats<24><<<nb * 24, blk, 0, stream>>>(partials, stats, NBT);

        conv2_sauvola<<<cgh, dim3(BDIM2), 0, stream>>>(
            bufB, stats, rf, bf, xc, kA, RA, alp, outc);
    }
}

// Round 9
// 380.528 us; speedup vs baseline: 1.0085x; 1.0085x over previous
//
#include <hip/hip_runtime.h>
#include <math.h>

#define BDIM 256
#define BDIM2 512
typedef __bf16 bf16;
typedef __bf16 bf16x4 __attribute__((ext_vector_type(4)));
typedef __bf16 bf16x8 __attribute__((ext_vector_type(8)));
typedef float f32x4 __attribute__((ext_vector_type(4)));
typedef float f32x2 __attribute__((ext_vector_type(2)));

template <bool V> struct BC { static constexpr bool value = V; };

constexpr int B_ = 4, H_ = 768, W_ = 768;
constexpr int HW_ = H_ * W_;                 // 589824
constexpr int TS = 16;                       // conv spatial tile 16x16
constexpr int NTB = W_ / TS;                 // 48
constexpr int NBLK = HW_ / (TS * TS);        // 2304 blocks per sample
// head tile: 16 rows x 32 cols
constexpr int TSR = 16, TSC = 32;
constexpr int NTBC = W_ / TSC;               // 24
constexpr int NBLKH = (H_ / TSR) * NTBC;     // 1152 per sample

// scratch carved from the TAIL of d_out (written before read each iteration;
// the final conv2_sauvola of the last chunk overwrites it after last use):
constexpr int PMAX_FLOATS = 4 * NBLK * 48;          // 442368
constexpr int OUT_ELEMS   = B_ * HW_;               // 2359296

// XCD-aware bijective swizzle (R7, verified: L6 FETCH 55->46MB, dur 98->72):
// hw blocks {k,k+8,...} all dispatch to XCD k; remap makes them process
// CONSECUTIVE tiles -> halo overlap + layer->layer reuse hit per-XCD L2.
// Requires n%8==0 (all grids are).
__device__ inline int xcd_swz(int b, int n) {
    const int q = n >> 3;
    return (b & 7) * q + (b >> 3);
}

// ---------------------------------------------------------------------------
// Weight repack: [COUT][CIN][3][3] fp32 -> padded bf16 [NT*16][KPP],
// k = tap*CINP + ci, zero everywhere outside (n<COUT, tap<9, ci<CIN).
// ---------------------------------------------------------------------------
__device__ void repack_one(const float* __restrict__ src, bf16* __restrict__ dst,
                           int CIN, int CINP, int COUT, int NT16, int KPP)
{
    const int n_ = NT16 * KPP;
    for (int idx = threadIdx.x; idx < n_; idx += BDIM) {
        const int n = idx / KPP, k = idx - n * KPP;
        const int tap = k / CINP, ci = k - tap * CINP;
        float v = 0.f;
        if (n < COUT && tap < 9 && ci < CIN)
            v = src[(n * CIN + ci) * 9 + tap];
        dst[idx] = (bf16)v;
    }
}

__global__ __launch_bounds__(BDIM) void repack_all(
    const float* w0, const float* w1, const float* w2, const float* w3,
    const float* w4, const float* w5, const float* wf,
    bf16* r0, bf16* r1, bf16* r2, bf16* r3, bf16* r4, bf16* r5, bf16* rf)
{
    switch (blockIdx.x) {
        case 0: repack_one(w0, r0, 1,  8,  4,  16, 104); break;
        case 1: repack_one(w1, r1, 4,  8,  8,  16, 104); break;
        case 2: repack_one(w2, r2, 8,  8,  12, 16, 104); break;
        case 3: repack_one(w3, r3, 12, 16, 16, 16, 168); break;
        case 4: repack_one(w4, r4, 16, 16, 20, 32, 168); break;
        case 5: repack_one(w5, r5, 20, 24, 24, 32, 232); break;
        case 6: repack_one(wf, rf, 24, 24, 6,  16, 232); break;
    }
}

// ---------------------------------------------------------------------------
// bf16-MFMA conv 3x3 (dilated, SAME) + bias, NHWC, TS=16 tiles, 256 thr.
// R9: staging reverted to R7's simple form — R8's 2-deep pipeline REGRESSED
// here (+6us on L6): staging is the FIRST phase of the kernel, there is no
// compute to hide the prefetched load under, and the masked second-iteration
// state only added overhead. (T14 lesson: issue-early needs a partner phase.)
// LESSONS pinned: (R4) TS=32 halves occupancy — NO; (R5/R11) NO high-rate
// device atomics/fences — 74ns per same-line RMW. Stats = per-block
// partials (transposed, coalesced) + tiny reduce kernel.
// Stats layout: prevStats[c] = (scale, beta) = (invstd, -mean*invstd).
// ---------------------------------------------------------------------------
template <int CIN, int CINP, int COUT, int DIL, bool FIRST>
__global__ __launch_bounds__(BDIM) void conv_mfma(
    const void* __restrict__ inv,        // FIRST: fp32 x; else bf16 y_prev
    const float* __restrict__ prevStats, // [nb][CIN][2] (scale, beta)
    const bf16* __restrict__ wp,         // packed [NT*16][KPP]
    const float* __restrict__ bias,      // [COUT] fp32
    bf16* __restrict__ y,                // [nb][H][W][COUT]
    float* __restrict__ partials,        // [2*COUT][nb*NBLK]
    int NBT)                             // nb*NBLK
{
    constexpr int TW = TS + 2 * DIL;
    constexpr int KP = ((9 * CINP + 31) / 32) * 32;
    constexpr int KPP = KP + 8;
    constexpr int NT = (COUT + 15) / 16;
    constexpr int KS = KP / 32;
    constexpr int CSTR = (CINP == 16) ? 24 : CINP;   // multiple of 8 (b128 align)
    __shared__ __align__(16) bf16 tile[TW * TW * CSTR];
    __shared__ float sred[4][2 * COUT];

    const int bid = xcd_swz(blockIdx.x, gridDim.x);
    const int s = bid / NBLK;
    const int blk = bid - s * NBLK;
    const int ti = blk / NTB, tj = blk - ti * NTB;
    const int i0 = ti * TS - DIL, j0 = tj * TS - DIL;
    const int t = threadIdx.x;
    const bool interior = (i0 >= 0) & (j0 >= 0) &
                          (i0 + TW <= H_) & (j0 + TW <= W_);

    // ---- stage halo tile (vector loads, packed LDS writes) ----
    const float* ps = prevStats + s * 2 * CIN;
    auto stage = [&](auto bc) {
        constexpr bool IN = decltype(bc)::value;
        for (int loc = t; loc < TW * TW; loc += BDIM) {
            const int rr = loc / TW, cc = loc - rr * TW;
            const int gi = i0 + rr, gj = j0 + cc;
            bool ok = true;
            if constexpr (!IN)
                ok = (gi >= 0) & (gi < H_) & (gj >= 0) & (gj < W_);
            float lv[CSTR];
#pragma unroll
            for (int c = 0; c < CSTR; ++c) lv[c] = 0.f;
            if (ok) {
                if constexpr (FIRST) {
                    const float* xg = (const float*)inv + (size_t)s * HW_;
                    lv[0] = xg[(size_t)gi * W_ + gj];
                } else {
                    const bf16* ing = (const bf16*)inv +
                                      ((size_t)s * HW_ + (size_t)gi * W_ + gj) * CIN;
                    if constexpr (CIN % 8 == 0) {
#pragma unroll
                        for (int qq = 0; qq < CIN / 8; ++qq) {
                            bf16x8 raw = ((const bf16x8*)ing)[qq];
#pragma unroll
                            for (int u = 0; u < 8; ++u) {
                                const int ci = 8 * qq + u;
                                lv[ci] = fmaxf(fmaf((float)raw[u], ps[2 * ci], ps[2 * ci + 1]), 0.f);
                            }
                        }
                    } else {
#pragma unroll
                        for (int qq = 0; qq < CIN / 4; ++qq) {
                            bf16x4 raw = ((const bf16x4*)ing)[qq];
#pragma unroll
                            for (int u = 0; u < 4; ++u) {
                                const int ci = 4 * qq + u;
                                lv[ci] = fmaxf(fmaf((float)raw[u], ps[2 * ci], ps[2 * ci + 1]), 0.f);
                            }
                        }
                    }
                }
            }
            bf16* lp = tile + loc * CSTR;
#pragma unroll
            for (int g = 0; g < CSTR / 8; ++g) {
                bf16x8 pk;
#pragma unroll
                for (int u = 0; u < 8; ++u) pk[u] = (bf16)lv[8 * g + u];
                *(bf16x8*)(lp + 8 * g) = pk;
            }
        }
    };
    if (interior) stage(BC<true>{}); else stage(BC<false>{});
    __syncthreads();

    // ---- MFMA K-loop, software-pipelined 1 ks ahead ----
    const int wave = t >> 6, lane = t & 63, q = lane >> 4, ln = lane & 15;
    f32x4 acc[4][NT];
#pragma unroll
    for (int mt = 0; mt < 4; ++mt)
#pragma unroll
        for (int u = 0; u < NT; ++u) acc[mt][u] = (f32x4){0.f, 0.f, 0.f, 0.f};

    auto aOff = [&](int ks) -> int {
        int k0 = ks * 32 + q * 8;
        int tap = k0 / CINP;
        int ci0 = k0 - tap * CINP;
        if (tap > 8) { tap = 0; ci0 = 0; }   // padded k: B rows are zero
        const int ky = tap / 3, kx = tap - 3 * ky;
        return (ky * DIL * TW + kx * DIL) * CSTR + ci0;
    };

    bf16x8 bfr[NT], bfrN[NT];
    bf16x8 af[4], afN[4];
#pragma unroll
    for (int u = 0; u < NT; ++u)
        bfr[u] = *(const bf16x8*)&wp[(u * 16 + ln) * KPP + q * 8];
    {
        const int ao = aOff(0);
#pragma unroll
        for (int mt = 0; mt < 4; ++mt)
            af[mt] = *(const bf16x8*)&tile[((wave * 4 + mt) * TW + ln) * CSTR + ao];
    }

#pragma unroll
    for (int ks = 0; ks < KS; ++ks) {
        if (ks + 1 < KS) {
#pragma unroll
            for (int u = 0; u < NT; ++u)
                bfrN[u] = *(const bf16x8*)&wp[(u * 16 + ln) * KPP + (ks + 1) * 32 + q * 8];
            const int ao = aOff(ks + 1);
#pragma unroll
            for (int mt = 0; mt < 4; ++mt)
                afN[mt] = *(const bf16x8*)&tile[((wave * 4 + mt) * TW + ln) * CSTR + ao];
        }
#pragma unroll
        for (int mt = 0; mt < 4; ++mt)
#pragma unroll
            for (int u = 0; u < NT; ++u)
                acc[mt][u] = __builtin_amdgcn_mfma_f32_16x16x32_bf16(
                    af[mt], bfr[u], acc[mt][u], 0, 0, 0);
#pragma unroll
        for (int u = 0; u < NT; ++u) bfr[u] = bfrN[u];
#pragma unroll
        for (int mt = 0; mt < 4; ++mt) af[mt] = afN[mt];
    }

    // ---- bias + stats (registers), sred ----
#pragma unroll
    for (int u = 0; u < NT; ++u) {
        const int n = u * 16 + ln;
        const float bv = (n < COUT) ? bias[n] : 0.f;
        float s1 = 0.f, s2 = 0.f;
#pragma unroll
        for (int mt = 0; mt < 4; ++mt)
#pragma unroll
            for (int r = 0; r < 4; ++r) {
                const float v = acc[mt][u][r] + bv;
                acc[mt][u][r] = v;
                s1 += v; s2 += v * v;
            }
        s1 += __shfl_xor(s1, 16); s1 += __shfl_xor(s1, 32);
        s2 += __shfl_xor(s2, 16); s2 += __shfl_xor(s2, 32);
        if (lane < 16 && n < COUT) { sred[wave][n] = s1; sred[wave][COUT + n] = s2; }
    }
    __syncthreads();   // K-loop tile reads complete + sred visible
    if (t < 2 * COUT) {
        partials[(size_t)t * NBT + (size_t)s * NBLK + blk] =
            sred[0][t] + sred[1][t] + sred[2][t] + sred[3][t];
    }

    // ---- out-stage into LDS (reuse tile), then coalesced global stores ----
    bf16* ost = tile;   // 256*COUT bf16 <= tile capacity for all layers
#pragma unroll
    for (int u = 0; u < NT; ++u) {
        const int n = u * 16 + ln;
        if (n < COUT) {
#pragma unroll
            for (int mt = 0; mt < 4; ++mt)
#pragma unroll
                for (int r = 0; r < 4; ++r) {
                    const int pl = (wave * 4 + mt) * 16 + q * 4 + r;
                    ost[pl * COUT + n] = (bf16)acc[mt][u][r];
                }
        }
    }
    __syncthreads();

    const int lr = t >> 4, lc = t & 15;
    bf16* yp = y + (size_t)s * HW_ * COUT +
               ((size_t)(ti * TS + lr) * W_ + (tj * TS + lc)) * COUT;
    const bf16* sp = ost + t * COUT;
    if constexpr (COUT % 8 == 0) {
#pragma unroll
        for (int g = 0; g < COUT / 8; ++g)
            ((bf16x8*)yp)[g] = ((const bf16x8*)sp)[g];
    } else {
#pragma unroll
        for (int g = 0; g < COUT / 4; ++g)
            ((bf16x4*)yp)[g] = ((const bf16x4*)sp)[g];
    }
}

// ---------------------------------------------------------------------------
// Reduce transposed partials -> (scale, beta) per (sample, channel):
// scale = invstd, beta = -mean*invstd  (consumer norm = fma(raw,scale,beta))
// ---------------------------------------------------------------------------
template <int COUT>
__global__ __launch_bounds__(BDIM) void reduce_stats(
    const float* __restrict__ partials, float* __restrict__ stats, int NBT)
{
    const int s = blockIdx.x / COUT;
    const int co = blockIdx.x - s * COUT;
    const float* P1 = partials + (size_t)co * NBT + (size_t)s * NBLK;
    const float* P2 = partials + (size_t)(COUT + co) * NBT + (size_t)s * NBLK;
    float s1 = 0.f, s2 = 0.f;
    for (int k = threadIdx.x; k < NBLK; k += BDIM) {
        s1 += P1[k];
        s2 += P2[k];
    }
#pragma unroll
    for (int off = 32; off; off >>= 1) {
        s1 += __shfl_xor(s1, off);
        s2 += __shfl_xor(s2, off);
    }
    __shared__ float l1[4], l2[4];
    const int lane = threadIdx.x & 63, wave = threadIdx.x >> 6;
    if (lane == 0) { l1[wave] = s1; l2[wave] = s2; }
    __syncthreads();
    if (threadIdx.x == 0) {
        float t1 = l1[0] + l1[1] + l1[2] + l1[3];
        float t2 = l2[0] + l2[1] + l2[2] + l2[3];
        float m = t1 / (float)HW_;
        float var = t2 / (float)HW_ - m * m;
        const float rs = rsqrtf(var + 1e-5f);
        stats[((size_t)s * COUT + co) * 2 + 0] = rs;
        stats[((size_t)s * COUT + co) * 2 + 1] = -m * rs;
    }
}

// ---------------------------------------------------------------------------
// Merged head (16x32 tile, 512 threads, 1 px/thread): conv2 (24->6, dil 1,
// MFMA, folded norm of L5) + channel softmax (registers) + fused Sauvola via
// LOCAL 34x50 float2 integral image in LDS. Segmented scans + fast-math
// intrinsics (R7). R8's 2-deep staging KEPT here (helped ~3us): unlike the
// conv, the second group's loads hide under the first group's I12 writes.
// ---------------------------------------------------------------------------
__global__ __launch_bounds__(BDIM2) void conv2_sauvola(
    const bf16* __restrict__ in, const float* __restrict__ prevStats,
    const bf16* __restrict__ wp, const float* __restrict__ bias,
    const float* __restrict__ x,
    const float* __restrict__ kArr, const float* __restrict__ RArr,
    const float* __restrict__ alphaP, float* __restrict__ outp)
{
    constexpr int CIN = 24, CINP = 24, COUT = 6;
    constexpr int TWR = TSR + 2;          // 18 halo rows
    constexpr int TWC = TSC + 2;          // 34 halo cols
    constexpr int KPP = 232, KS = 7, CSTR = 24;
    constexpr int R9 = 9;                 // max window radius (19>>1)
    constexpr int HR = TSR + 2 * R9;      // 34 I12 data rows
    constexpr int HC = TSC + 2 * R9;      // 50 I12 data cols
    constexpr int IST = 51;               // integral-image stride in float2
    constexpr int SLOG_STR = 7;           // gcd(7,32)=1 -> conflict-light
    constexpr int NLOC = TWR * TWC;       // 612 -> 2 iterations @512
    constexpr int N8 = CIN / 8;           // 3
    __shared__ __align__(16) bf16 tile[NLOC * CSTR];          // 29376 B
    __shared__ __align__(16) f32x2 I12[(HR + 1) * IST];       // 14280 B

    const int bid = xcd_swz(blockIdx.x, gridDim.x);
    const int s = bid / NBLKH;
    const int blk = bid - s * NBLKH;
    const int ti = blk / NTBC, tj = blk - ti * NTBC;   // ti 0..47, tj 0..23
    const int i0 = ti * TSR - 1, j0 = tj * TSC - 1;
    const int is0 = ti * TSR - R9, js0 = tj * TSC - R9;
    const int t = threadIdx.x;
    const float* xs = x + (size_t)s * HW_;
    const bool interior = (is0 >= 0) & (js0 >= 0) &
                          (is0 + HR <= H_) & (js0 + HC <= W_);

    // ---- stage conv2 tile (2-deep) + 34x50 x-halo into I12 (2x 2-deep) ----
    const float* ps = prevStats + s * 2 * CIN;
    auto stage = [&](auto bc) {
        constexpr bool IN = decltype(bc)::value;
        // conv tile: iterations {t, t+512}
        {
            const int loc1 = t + BDIM2;
            const bool act1 = loc1 < NLOC;
            int gi[2], gj[2];
            bool ok[2];
            {
                const int rr0 = t / TWC, cc0 = t - rr0 * TWC;
                gi[0] = i0 + rr0; gj[0] = j0 + cc0;
                const int rr1 = loc1 / TWC, cc1 = loc1 - rr1 * TWC;
                gi[1] = i0 + rr1; gj[1] = j0 + cc1;
            }
            if constexpr (IN) {
                ok[0] = true; ok[1] = act1;
            } else {
                ok[0] = (gi[0] >= 0) & (gi[0] < H_) & (gj[0] >= 0) & (gj[0] < W_);
                ok[1] = act1 & (gi[1] >= 0) & (gi[1] < H_) & (gj[1] >= 0) & (gj[1] < W_);
            }
            bf16x8 r8[2][N8];
#pragma unroll
            for (int d = 0; d < 2; ++d) {
                if (ok[d]) {
                    const bf16* ing = in +
                        ((size_t)s * HW_ + (size_t)gi[d] * W_ + gj[d]) * CIN;
#pragma unroll
                    for (int qq = 0; qq < N8; ++qq)
                        r8[d][qq] = ((const bf16x8*)ing)[qq];
                }
            }
#pragma unroll
            for (int d = 0; d < 2; ++d) {
                if (d == 1 && !act1) break;
                float lv[CSTR];
#pragma unroll
                for (int c = 0; c < CSTR; ++c) lv[c] = 0.f;
                if (ok[d]) {
#pragma unroll
                    for (int qq = 0; qq < N8; ++qq)
#pragma unroll
                        for (int u = 0; u < 8; ++u) {
                            const int ci = 8 * qq + u;
                            lv[ci] = fmaxf(fmaf((float)r8[d][qq][u], ps[2 * ci], ps[2 * ci + 1]), 0.f);
                        }
                }
                bf16* lp = tile + (t + d * BDIM2) * CSTR;
#pragma unroll
                for (int g = 0; g < CSTR / 8; ++g) {
                    bf16x8 pk;
#pragma unroll
                    for (int u = 0; u < 8; ++u) pk[u] = (bf16)lv[8 * g + u];
                    *(bf16x8*)(lp + 8 * g) = pk;
                }
            }
        }
        // I12 halo: 1700 locs -> two 2-deep groups
#pragma unroll
        for (int base = 0; base < HR * HC; base += 2 * BDIM2) {
            const int l0 = base + t, l1 = base + BDIM2 + t;
            const bool a0 = l0 < HR * HC, a1 = l1 < HR * HC;
            float v0 = 0.f, v1 = 0.f;
            int rr0 = 0, cc0 = 0, rr1 = 0, cc1 = 0;
            if (a0) {
                rr0 = l0 / HC; cc0 = l0 - rr0 * HC;
                const int gi = is0 + rr0, gj = js0 + cc0;
                if constexpr (IN) v0 = xs[(size_t)gi * W_ + gj];
                else if ((gi >= 0) & (gi < H_) & (gj >= 0) & (gj < W_))
                    v0 = xs[(size_t)gi * W_ + gj];
            }
            if (a1) {
                rr1 = l1 / HC; cc1 = l1 - rr1 * HC;
                const int gi = is0 + rr1, gj = js0 + cc1;
                if constexpr (IN) v1 = xs[(size_t)gi * W_ + gj];
                else if ((gi >= 0) & (gi < H_) & (gj >= 0) & (gj < W_))
                    v1 = xs[(size_t)gi * W_ + gj];
            }
            if (a0) I12[(rr0 + 1) * IST + cc0 + 1] = (f32x2){v0, v0 * v0};
            if (a1) I12[(rr1 + 1) * IST + cc1 + 1] = (f32x2){v1, v1 * v1};
        }
    };
    if (interior) stage(BC<true>{}); else stage(BC<false>{});
    for (int idx = t; idx < IST + HR; idx += BDIM2) {
        if (idx < IST) I12[idx] = (f32x2){0.f, 0.f};              // row 0
        else I12[(idx - IST + 1) * IST] = (f32x2){0.f, 0.f};      // col 0
    }
    __syncthreads();

    // ---- conv2 MFMA K-loop: 8 waves x 4 M-tiles (M=512 px) ----
    const int wave = t >> 6, lane = t & 63, q = lane >> 4, ln = lane & 15;
    f32x4 acc[4];
#pragma unroll
    for (int mt = 0; mt < 4; ++mt) acc[mt] = (f32x4){0.f, 0.f, 0.f, 0.f};

    auto aOff = [&](int ks) -> int {
        int k0 = ks * 32 + q * 8;
        int tap = k0 / CINP;
        int ci0 = k0 - tap * CINP;
        if (tap > 8) { tap = 0; ci0 = 0; }
        const int ky = tap / 3, kx = tap - 3 * ky;
        return (ky * TWC + kx) * CSTR + ci0;
    };

#pragma unroll
    for (int ks = 0; ks < KS; ++ks) {
        const bf16x8 bfr = *(const bf16x8*)&wp[ln * KPP + ks * 32 + q * 8];
        const int ao = aOff(ks);
#pragma unroll
        for (int mt = 0; mt < 4; ++mt) {
            const int Mt = wave * 4 + mt;                 // 0..31
            const bf16x8 af = *(const bf16x8*)
                &tile[(((Mt >> 1)) * TWC + (Mt & 1) * 16 + ln) * CSTR + ao];
            acc[mt] = __builtin_amdgcn_mfma_f32_16x16x32_bf16(af, bfr, acc[mt], 0, 0, 0);
        }
    }
    __syncthreads();   // done reading tile -> reuse as logits

    // ---- phase A: logits -> slog ; row-SEGMENT scan (68 thr, 25 iters) ----
    float* slog = (float*)tile;            // 512*7*4 = 14336 B <= 29376 B
    const float bv = (ln < COUT) ? bias[ln] : 0.f;
#pragma unroll
    for (int mt = 0; mt < 4; ++mt)
#pragma unroll
        for (int r = 0; r < 4; ++r)
            if (ln < COUT) {
                const int pl = (wave * 4 + mt) * 16 + q * 4 + r;   // 0..511
                slog[pl * SLOG_STR + ln] = acc[mt][r] + bv;
            }
    if (t < 68) {
        const int row = (t < 34 ? t : t - 34) + 1;
        const int c0 = (t < 34) ? 1 : 26;
        f32x2* p = I12 + row * IST + c0;
        f32x2 a = p[0];
#pragma unroll 5
        for (int c = 1; c < 25; ++c) { a += p[c]; p[c] = a; }
    }
    __syncthreads();

    // ---- row fixup: cols 26..50 += row-left total (850 cells, all thr) ----
    for (int idx = t; idx < 34 * 25; idx += BDIM2) {
        const int row = idx / 25 + 1, col = idx % 25 + 26;
        I12[row * IST + col] += I12[row * IST + 25];
    }
    __syncthreads();

    // ---- col-SEGMENT scan (100 thr, 17 iters) + softmax (all thr) ----
    if (t < 100) {
        const int col = (t < 50 ? t : t - 50) + 1;
        const int r0 = (t < 50) ? 1 : 18;
        f32x2* p = I12 + r0 * IST + col;
        f32x2 a = *p;
#pragma unroll 4
        for (int r = 1; r < 17; ++r) { a += p[r * IST]; p[r * IST] = a; }
    }
    float e0[COUT];
    {
        float mx = slog[t * SLOG_STR];
#pragma unroll
        for (int co = 1; co < COUT; ++co) mx = fmaxf(mx, slog[t * SLOG_STR + co]);
        float sm = 0.f;
#pragma unroll
        for (int co = 0; co < COUT; ++co) { e0[co] = __expf(slog[t * SLOG_STR + co] - mx); sm += e0[co]; }
        const float inv = __builtin_amdgcn_rcpf(sm);
#pragma unroll
        for (int co = 0; co < COUT; ++co) e0[co] *= inv;
    }
    // per-window fused constants: th = Ex*(1 + k*(dev/R - 1)) = Ex*fma(dev,c0,c1)
    float c0w[6], c1w[6];
#pragma unroll
    for (int wi = 0; wi < 6; ++wi) {
        const float kk = kArr[wi], rr = RArr[wi];
        c0w[wi] = kk / rr;
        c1w[wi] = 1.f - kk;
    }
    // hoist per-pixel globals (load latency hides under the scans)
    const int pr0 = t >> 5, pc0 = t & 31;          // px: rows 0..15, cols 0..31
    const int gi0 = ti * TSR + pr0, gj0 = tj * TSC + pc0;
    const float xv0 = xs[(size_t)gi0 * W_ + gj0];
    const float alpha = alphaP[0];
    __syncthreads();

    // ---- col fixup: rows 18..34 += row-17 total (850 cells, all thr) ----
    for (int idx = t; idx < 17 * 50; idx += BDIM2) {
        const int row = idx / 50 + 18, col = idx % 50 + 1;
        I12[row * IST + col] += I12[17 * IST + col];
    }
    __syncthreads();   // integral image complete

    // ---- phase C: Sauvola (f = e0[] in registers) ----
    const int wins[6] = {3, 5, 7, 11, 15, 19};
    const float invc_tab[6] = {1.f / 9.f,  1.f / 25.f,  1.f / 49.f,
                               1.f / 121.f, 1.f / 225.f, 1.f / 361.f};
    float th1 = 0.f;
    if (interior) {
#pragma unroll
        for (int wi = 0; wi < 6; ++wi) {
            const int r = wins[wi] >> 1;
            const float invc = invc_tab[wi];
            const int top = pr0 + R9 - r, bot = pr0 + R9 + r + 1;
            const int lef = pc0 + R9 - r, rig = pc0 + R9 + r + 1;
            const f32x2 Atl = I12[top * IST + lef];
            const f32x2 Atr = I12[top * IST + rig];
            const f32x2 Abl = I12[bot * IST + lef];
            const f32x2 Abr = I12[bot * IST + rig];
            const f32x2 sm2 = Abr - Atr - Abl + Atl;
            const float Ex = sm2.x * invc;
            const float Ex2 = sm2.y * invc;
            const float dev = __builtin_amdgcn_sqrtf(fmaxf(Ex2 - Ex * Ex, 1e-6f));
            const float th = Ex * fmaf(dev, c0w[wi], c1w[wi]);
            th1 = fmaf(e0[wi], th, th1);
        }
    } else {
#pragma unroll
        for (int wi = 0; wi < 6; ++wi) {
            const int r = wins[wi] >> 1;
            const int r0 = max(gi0 - r, 0), r1i = min(gi0 + r, H_ - 1);
            const int c0 = max(gj0 - r, 0), c1 = min(gj0 + r, W_ - 1);
            const float invc = __builtin_amdgcn_rcpf((float)((r1i - r0 + 1) * (c1 - c0 + 1)));
            const int top = pr0 + R9 - r, bot = pr0 + R9 + r + 1;
            const int lef = pc0 + R9 - r, rig = pc0 + R9 + r + 1;
            const f32x2 Atl = I12[top * IST + lef];
            const f32x2 Atr = I12[top * IST + rig];
            const f32x2 Abl = I12[bot * IST + lef];
            const f32x2 Abr = I12[bot * IST + rig];
            const f32x2 sm2 = Abr - Atr - Abl + Atl;
            const float Ex = sm2.x * invc;
            const float Ex2 = sm2.y * invc;
            const float dev = __builtin_amdgcn_sqrtf(fmaxf(Ex2 - Ex * Ex, 1e-6f));
            const float th = Ex * fmaf(dev, c0w[wi], c1w[wi]);
            th1 = fmaf(e0[wi], th, th1);
        }
    }
    outp[(size_t)s * HW_ + (size_t)gi0 * W_ + gj0] = (xv0 - th1) * alpha;
}

// ---------------------------------------------------------------------------
extern "C" void kernel_launch(void* const* d_in, const int* in_sizes, int n_in,
                              void* d_out, int out_size, void* d_ws, size_t ws_size,
                              hipStream_t stream) {
    const float* x   = (const float*)d_in[0];
    const float* w0  = (const float*)d_in[1];  const float* b0 = (const float*)d_in[2];
    const float* w1  = (const float*)d_in[3];  const float* b1 = (const float*)d_in[4];
    const float* w2  = (const float*)d_in[5];  const float* b2 = (const float*)d_in[6];
    const float* w3  = (const float*)d_in[7];  const float* b3 = (const float*)d_in[8];
    const float* w4  = (const float*)d_in[9];  const float* b4 = (const float*)d_in[10];
    const float* w5  = (const float*)d_in[11]; const float* b5 = (const float*)d_in[12];
    const float* wf  = (const float*)d_in[13]; const float* bf = (const float*)d_in[14];
    const float* kA  = (const float*)d_in[15];
    const float* RA  = (const float*)d_in[16];
    const float* alp = (const float*)d_in[17];
    float* out = (float*)d_out;
    (void)n_in; (void)in_sizes; (void)out_size;

    // partials + stats live in the TAIL of d_out: each iteration writes them
    // before reading; only the final chunk's conv2_sauvola overwrites the
    // tail, and that happens after the last partials/stats use.
    float* partials = out + (OUT_ELEMS - PMAX_FLOATS - 256);
    float* stats    = out + (OUT_ELEMS - 224);

    // ---- choose samples-per-launch from ws_size (deterministic) ----
    auto need = [](int nb) -> size_t {
        size_t o = 0;
        auto al = [&](size_t bytes) { o += (bytes + 255) & ~(size_t)255; };
        al((size_t)nb * HW_ * 20 * 2);          // bufA (bf16)
        al((size_t)nb * HW_ * 24 * 2);          // bufB (bf16)
        al(1664 * 2); al(1664 * 2); al(1664 * 2); al(2688 * 2);
        al(5376 * 2); al(7424 * 2); al(3712 * 2);
        return o;
    };
    int nb = 1;
    if (ws_size >= need(4)) nb = 4;
    else if (ws_size >= need(2)) nb = 2;

    char* ws = (char*)d_ws;
    size_t off = 0;
    auto alloc = [&](size_t bytes) -> void* {
        void* p = ws + off;
        off += (bytes + 255) & ~(size_t)255;
        return p;
    };
    bf16*  bufA = (bf16*)alloc((size_t)nb * HW_ * 20 * 2);
    bf16*  bufB = (bf16*)alloc((size_t)nb * HW_ * 24 * 2);
    bf16* r0 = (bf16*)alloc(1664 * 2);
    bf16* r1 = (bf16*)alloc(1664 * 2);
    bf16* r2 = (bf16*)alloc(1664 * 2);
    bf16* r3 = (bf16*)alloc(2688 * 2);
    bf16* r4 = (bf16*)alloc(5376 * 2);
    bf16* r5 = (bf16*)alloc(7424 * 2);
    bf16* rf = (bf16*)alloc(3712 * 2);

    const dim3 blk(BDIM);
    const int cgc = nb * NBLK;      // conv grid (TS=16)
    const int cgh = nb * NBLKH;     // head grid (16x32)
    const int NBT = nb * NBLK;

    repack_all<<<7, blk, 0, stream>>>(w0, w1, w2, w3, w4, w5, wf,
                                      r0, r1, r2, r3, r4, r5, rf);

    for (int it = 0; it < B_ / nb; ++it) {
        const float* xc   = x   + (size_t)it * nb * HW_;
        float*       outc = out + (size_t)it * nb * HW_;

        conv_mfma<1, 8, 4, 1, true><<<cgc, blk, 0, stream>>>(xc, nullptr, r0, b0, bufA, partials, NBT);
        reduce_stats<4><<<nb * 4, blk, 0, stream>>>(partials, stats, NBT);

        conv_mfma<4, 8, 8, 2, false><<<cgc, blk, 0, stream>>>(bufA, stats, r1, b1, bufB, partials, NBT);
        reduce_stats<8><<<nb * 8, blk, 0, stream>>>(partials, stats, NBT);

        conv_mfma<8, 8, 12, 2, false><<<cgc, blk, 0, stream>>>(bufB, stats, r2, b2, bufA, partials, NBT);
        reduce_stats<12><<<nb * 12, blk, 0, stream>>>(partials, stats, NBT);

        conv_mfma<12, 16, 16, 2, false><<<cgc, blk, 0, stream>>>(bufA, stats, r3, b3, bufB, partials, NBT);
        reduce_stats<16><<<nb * 16, blk, 0, stream>>>(partials, stats, NBT);

        conv_mfma<16, 16, 20, 2, false><<<cgc, blk, 0, stream>>>(bufB, stats, r4, b4, bufA, partials, NBT);
        reduce_stats<20><<<nb * 20, blk, 0, stream>>>(partials, stats, NBT);

        conv_mfma<20, 24, 24, 2, false><<<cgc, blk, 0, stream>>>(bufA, stats, r5, b5, bufB, partials, NBT);
        reduce_stats<24><<<nb * 24, blk, 0, stream>>>(partials, stats, NBT);

        conv2_sauvola<<<cgh, dim3(BDIM2), 0, stream>>>(
            bufB, stats, rf, bf, xc, kA, RA, alp, outc);
    }
}